// Round 1
// baseline (958.747 us; speedup 1.0000x reference)
//
#include <hip/hip_runtime.h>
#include <hip/hip_bf16.h>

// Problem constants (fixed by the reference):
//   N=10000, L=5, A=6, C=20, C2=20
//   pairs = L*A = 30; stats per n = L*A*C2 = 600; elems per pair = C*C2 = 400
//   elems per n (posterior / rightmost) = 12000 (= 3000 float4)
// Output layout (flat concat): p_Q [N*C = 200000] | posterior [120M] | rightmost [120M]

#define PQ_COUNT   200000
#define POST_OFF   200000
#define RT_OFF     (200000 + 120000000)

__global__ __launch_bounds__(256) void cgmm_kernel(
    const float* __restrict__ stats,   // [N,5,6,20]
    const float* __restrict__ layerS,  // [5]
    const float* __restrict__ arcS,    // [5,6]
    const float* __restrict__ T,       // [5,6,20,20]
    float* __restrict__ out)
{
    __shared__ __attribute__((aligned(16))) float s[600]; // stats[n]
    __shared__ float invb[30];   // 1/neighbDim per (l,a) pair
    __shared__ float wgt[30];    // layerS[l]*arcS[l,a]
    __shared__ float red[200];   // p_Q partial reduction

    const int n = blockIdx.x;
    const int t = threadIdx.x;

    // Stage this n's stats into LDS (600 floats, coalesced).
    const float* sn = stats + (size_t)n * 600;
    for (int i = t; i < 600; i += 256) s[i] = sn[i];
    __syncthreads();

    // Per-(l,a): inverse neighbor dim + layer*arc weight.
    if (t < 30) {
        float sum = 0.f;
        #pragma unroll
        for (int j = 0; j < 20; ++j) sum += s[t * 20 + j];
        invb[t] = (sum == 0.f) ? 1.f : 1.f / sum;
        wgt[t]  = layerS[t / 6] * arcS[t];
    }
    __syncthreads();

    const float4* T4 = (const float4*)T;          // 3000 float4
    const float4* s4 = (const float4*)s;          // 150 float4
    float4* post4 = (float4*)(out + POST_OFF) + (size_t)n * 3000;
    float4* rt4o  = (float4*)(out + RT_OFF)   + (size_t)n * 3000;

    // 200 active threads cover 2 (l,a) pairs per iteration.
    // Thread t -> pair offset t/100, within-pair float4 index r = t%100.
    // r = c*5 + q  (c in [0,20), q in [0,5)) -> c is FIXED per thread,
    // so the p_Q partial (sum of posterior over l,a,c2 at fixed c) is one register.
    float acc = 0.f;
    if (t < 200) {
        const int r = t % 100;
        const int q = r % 5;          // which float4 of the c2 row
        #pragma unroll
        for (int pb = 0; pb < 30; pb += 2) {
            const int p = pb + t / 100;         // pair index (l*6+a)
            const float inv = invb[p];
            const float w   = wgt[p];
            const float4 tv = T4[p * 100 + r];  // L2-resident (48 KB total)
            const float4 sv = s4[p * 5 + q];    // stats[n, pair, 4*q .. 4*q+3]
            float4 rt;
            rt.x = tv.x * sv.x * inv;
            rt.y = tv.y * sv.y * inv;
            rt.z = tv.z * sv.z * inv;
            rt.w = tv.w * sv.w * inv;
            float4 po;
            po.x = rt.x * w; po.y = rt.y * w;
            po.z = rt.z * w; po.w = rt.w * w;
            // Global float4 index = n*3000 + pb*100 + t : contiguous across the
            // 200 active threads -> fully coalesced 16 B/lane stores.
            rt4o [p * 100 + r] = rt;
            post4[p * 100 + r] = po;
            acc += po.x + po.y + po.z + po.w;
        }
        red[t] = acc;
    }
    __syncthreads();

    // p_Q[n,c] = sum over the 10 threads owning c (5 per pair-slot * 2 slots).
    if (t < 20) {
        float pq = 0.f;
        #pragma unroll
        for (int k = 0; k < 5; ++k)
            pq += red[t * 5 + k] + red[100 + t * 5 + k];
        out[(size_t)n * 20 + t] = pq;
    }
}

extern "C" void kernel_launch(void* const* d_in, const int* in_sizes, int n_in,
                              void* d_out, int out_size, void* d_ws, size_t ws_size,
                              hipStream_t stream) {
    const float* stats  = (const float*)d_in[0];
    const float* layerS = (const float*)d_in[1];
    const float* arcS   = (const float*)d_in[2];
    const float* T      = (const float*)d_in[3];
    float* out = (float*)d_out;
    cgmm_kernel<<<dim3(10000), dim3(256), 0, stream>>>(stats, layerS, arcS, T, out);
}